// Round 6
// baseline (3960.938 us; speedup 1.0000x reference)
//
#include <hip/hip_runtime.h>
#include <math.h>

// PraxisNano: B=4, T=8192, H=512, E=2048, C=64, stride=32
// Inputs: float32. Output: float32 (reference is pure f32). Internal: bf16 MFMA.
#define TB 4
#define TT 8192
#define TH 512
#define TE 2048
#define NCHUNK 256

typedef unsigned short u16;
typedef short bf8v __attribute__((ext_vector_type(8)));   // 8 bf16 MFMA frag
typedef float f4v __attribute__((ext_vector_type(4)));    // MFMA accumulator

__device__ __forceinline__ float bu2f(u16 u) {
    unsigned int x = ((unsigned int)u) << 16; float f; __builtin_memcpy(&f, &x, 4); return f;
}
__device__ __forceinline__ u16 f2bu(float f) {
    unsigned int x; __builtin_memcpy(&x, &f, 4);
    x = x + 0x7fffu + ((x >> 16) & 1u);   // RNE
    return (u16)(x >> 16);
}

// ---------------- composite TriLinear matrix, transposed: Mt[s][t] = ((W2.tri)(W1.tri))[t][s]
__global__ __launch_bounds__(256) void make_Mt(const float* __restrict__ W1,
                                               const float* __restrict__ W2,
                                               float* __restrict__ Mt) {
    __shared__ float w1[64 * 64];
    __shared__ float w2[64 * 64];
    for (int i = threadIdx.x; i < 4096; i += 256) { w1[i] = W1[i]; w2[i] = W2[i]; }
    __syncthreads();
    for (int i = threadIdx.x; i < 4096; i += 256) {
        int t = i >> 6, s = i & 63;
        float a = 0.f;
        if (t >= s) for (int k = s; k <= t; ++k) a += w2[t * 64 + k] * w1[k * 64 + s];
        Mt[s * 64 + t] = a;
    }
}

// ---------------- transpose f32 (R x C) -> bf16 (C x R)
__global__ __launch_bounds__(256) void transpose_b(const float* __restrict__ in,
                                                   u16* __restrict__ out, int R, int C) {
    __shared__ u16 tile[64][65];
    const int bx = blockIdx.x, by = blockIdx.y;
    const int tx = threadIdx.x & 63, ty = threadIdx.x >> 6;
#pragma unroll
    for (int i = 0; i < 16; ++i) {
        int r = ty + i * 4;
        tile[r][tx] = f2bu(in[(size_t)(by * 64 + r) * C + bx * 64 + tx]);
    }
    __syncthreads();
#pragma unroll
    for (int i = 0; i < 16; ++i) {
        int r = ty + i * 4;
        out[(size_t)(bx * 64 + r) * R + by * 64 + tx] = tile[tx][r];
    }
}

// ---------------- LN1 stats per x-row (mean, rstd), x float32
__global__ __launch_bounds__(256) void ln_stats(const float* __restrict__ x,
                                                float2* __restrict__ st) {
    const int wave = threadIdx.x >> 6, lane = threadIdx.x & 63;
    const size_t row = (size_t)blockIdx.x * 4 + wave;
    const float4* p = (const float4*)(x + row * TH);
    float4 a = p[lane * 2], b = p[lane * 2 + 1];
    float s = 0.f, q = 0.f;
    float v[8] = {a.x, a.y, a.z, a.w, b.x, b.y, b.z, b.w};
#pragma unroll
    for (int i = 0; i < 8; ++i) { s += v[i]; q += v[i] * v[i]; }
#pragma unroll
    for (int o = 32; o; o >>= 1) { s += __shfl_xor(s, o); q += __shfl_xor(q, o); }
    const float mean = s * (1.f / TH);
    float var = q * (1.f / TH) - mean * mean;
    if (var < 0.f) var = 0.f;
    if (lane == 0) st[row] = make_float2(mean, rsqrtf(var + 1e-5f));
}

// ---------------- LN2: bf16 rows in -> bf16 rows out, f32 gamma/beta
__global__ __launch_bounds__(256) void ln_rows(const u16* __restrict__ in,
                                               u16* __restrict__ out,
                                               const float* __restrict__ g,
                                               const float* __restrict__ b) {
    const int wave = threadIdx.x >> 6, lane = threadIdx.x & 63;
    const size_t row = (size_t)blockIdx.x * 4 + wave;
    uint4 raw = *((const uint4*)(in + row * TH) + lane);
    const u16* e = (const u16*)&raw;
    float v[8]; float s = 0.f, q = 0.f;
#pragma unroll
    for (int i = 0; i < 8; ++i) { v[i] = bu2f(e[i]); s += v[i]; q += v[i] * v[i]; }
#pragma unroll
    for (int o = 32; o; o >>= 1) { s += __shfl_xor(s, o); q += __shfl_xor(q, o); }
    const float mean = s * (1.f / TH);
    float var = q * (1.f / TH) - mean * mean;
    if (var < 0.f) var = 0.f;
    const float rstd = rsqrtf(var + 1e-5f);
    float4 g0 = ((const float4*)g)[lane * 2], g1 = ((const float4*)g)[lane * 2 + 1];
    float4 b0 = ((const float4*)b)[lane * 2], b1 = ((const float4*)b)[lane * 2 + 1];
    float ge[8] = {g0.x, g0.y, g0.z, g0.w, g1.x, g1.y, g1.z, g1.w};
    float be[8] = {b0.x, b0.y, b0.z, b0.w, b1.x, b1.y, b1.z, b1.w};
    u16 ov[8];
#pragma unroll
    for (int i = 0; i < 8; ++i) ov[i] = f2bu((v[i] - mean) * rstd * ge[i] + be[i]);
    *((uint4*)(out + row * TH) + lane) = *(uint4*)ov;
}

// ---------------- TriLinear for one slice, LN1 fused via stats; x float32
__global__ __launch_bounds__(256) void trilinear_f(const float* __restrict__ x,
                                                   const float2* __restrict__ st,
                                                   const float* __restrict__ g,
                                                   const float* __restrict__ bb,
                                                   const float* __restrict__ Mt,
                                                   u16* __restrict__ c2s,
                                                   int b, int n0) {
    const int ln = blockIdx.x;
    const int h = (blockIdx.y << 8) + threadIdx.x;
    const int base = (n0 + ln) * 32;
    const float gh = g[h], bh = bb[h];
    float acc[64];
#pragma unroll
    for (int t = 0; t < 64; ++t) acc[t] = 0.f;
    for (int s = 0; s < 64; ++s) {
        int pos = base + s; if (pos > TT - 1) pos = TT - 1;   // clamped rows hit only M==0 weights for read outputs
        const size_t ro = (size_t)b * TT + pos;
        const float2 mr = st[ro];
        const float cn = (x[ro * TH + h] - mr.x) * mr.y * gh + bh;
        const float* m = Mt + s * 64;
#pragma unroll
        for (int t = 0; t < 64; ++t) acc[t] += m[t] * cn;
    }
#pragma unroll
    for (int t = 0; t < 64; ++t) {
        int pos = base + t; if (pos > TT - 1) pos = TT - 1;
        const float resid = x[((size_t)b * TT + pos) * TH + h];
        c2s[(size_t)(ln * 64 + t) * TH + h] = f2bu(acc[t] + resid);
    }
}

// ---------------- MFMA GEMM, B^T input, register->LDS staging
// MODE 1: C = sin(acc + bias);  MODE 2: C = acc + bias + addp
template <int MODE>
__global__ __launch_bounds__(256) void gemm_bt(const u16* __restrict__ A,    // M x K bf16
                                               const u16* __restrict__ Bt,   // N x K bf16
                                               u16* __restrict__ C,          // M x N bf16
                                               const float* __restrict__ bias,
                                               const u16* __restrict__ addp,
                                               int N, int K) {
    __shared__ u16 lA[128 * 64];
    __shared__ u16 lB[128 * 64];
    const int tid = threadIdx.x;
    const int wave = tid >> 6;
    const int lane = tid & 63;
    const int wr = wave >> 1;
    const int wc = wave & 1;
    const int bm = blockIdx.y << 7;
    const int bn = blockIdx.x << 7;
    const int fr = lane & 15;
    const int fq = (lane >> 4) << 3;
    f4v acc[4][4] = {};

    for (int kb = 0; kb < K; kb += 64) {
        uint4 ra[4], rb[4];
#pragma unroll
        for (int i = 0; i < 4; ++i) {
            const int lin = i * 256 + tid;          // uint4 id in 128x64 tile
            const int row = lin >> 3, c8 = lin & 7;
            ra[i] = *((const uint4*)(A + (size_t)(bm + row) * K + kb) + c8);
            rb[i] = *((const uint4*)(Bt + (size_t)(bn + row) * K + kb) + c8);
        }
        __syncthreads();                            // previous iter's LDS reads done
#pragma unroll
        for (int i = 0; i < 4; ++i) {
            const int lin = i * 256 + tid;
            ((uint4*)lA)[lin] = ra[i];
            ((uint4*)lB)[lin] = rb[i];
        }
        __syncthreads();                            // writes visible
#pragma unroll
        for (int ks = 0; ks < 64; ks += 32) {
            bf8v af[4], bf[4];
#pragma unroll
            for (int mi = 0; mi < 4; ++mi)
                af[mi] = *(const bf8v*)(lA + ((wr << 6) + (mi << 4) + fr) * 64 + ks + fq);
#pragma unroll
            for (int ni = 0; ni < 4; ++ni)
                bf[ni] = *(const bf8v*)(lB + ((wc << 6) + (ni << 4) + fr) * 64 + ks + fq);
#pragma unroll
            for (int mi = 0; mi < 4; ++mi)
#pragma unroll
                for (int ni = 0; ni < 4; ++ni)
                    acc[mi][ni] = __builtin_amdgcn_mfma_f32_16x16x32_bf16(af[mi], bf[ni], acc[mi][ni], 0, 0, 0);
        }
    }

    const int rq = (lane >> 4) << 2;   // C/D: col=lane&15, row=(lane>>4)*4+reg (m89/m91)
#pragma unroll
    for (int mi = 0; mi < 4; ++mi) {
#pragma unroll
        for (int ni = 0; ni < 4; ++ni) {
            const int col = bn + (wc << 6) + (ni << 4) + fr;
            const float bv = bias[col];
#pragma unroll
            for (int r = 0; r < 4; ++r) {
                const int row = bm + (wr << 6) + (mi << 4) + rq + r;
                float v = acc[mi][ni][r] + bv;
                if (MODE == 1) v = sinf(v);
                else v += bu2f(addp[(size_t)row * N + col]);
                C[(size_t)row * N + col] = f2bu(v);
            }
        }
    }
}

// ---------------- per-slice gather -> FLOAT32 output
__global__ __launch_bounds__(256) void gather_slice(const u16* __restrict__ ocs,
                                                    const u16* __restrict__ carry,
                                                    float* __restrict__ outb,
                                                    int n0) {
    const int idx = blockIdx.x * 256 + threadIdx.x;   // vec8 id
    const int h8 = idx & 63;
    const int prow = idx >> 6;
    const int t = n0 * 32 + prow;
    const int n = t >> 5, c = t & 31;
    const int ln = n - n0;
    uint4 r1 = *((const uint4*)ocs + (size_t)(ln * 64 + c) * 64 + h8);
    const u16* e1 = (const u16*)&r1;
    float ov[8];
    if (n == 0) {
#pragma unroll
        for (int i = 0; i < 8; ++i) ov[i] = bu2f(e1[i]);
    } else {
        uint4 r0;
        if (ln == 0) r0 = *((const uint4*)carry + (size_t)(c + 32) * 64 + h8);
        else         r0 = *((const uint4*)ocs + (size_t)((ln - 1) * 64 + c + 32) * 64 + h8);
        const u16* e0 = (const u16*)&r0;
#pragma unroll
        for (int i = 0; i < 8; ++i) ov[i] = 0.5f * (bu2f(e1[i]) + bu2f(e0[i]));
    }
    float4* dst = (float4*)(outb + (size_t)idx * 8);
    dst[0] = make_float4(ov[0], ov[1], ov[2], ov[3]);
    dst[1] = make_float4(ov[4], ov[5], ov[6], ov[7]);
}

// ---------------- save last chunk of slice for next slice's boundary
__global__ __launch_bounds__(256) void save_carry(const u16* __restrict__ ocs,
                                                  u16* __restrict__ carry, int SC) {
    const int i = blockIdx.x * 256 + threadIdx.x;     // uint4 id, 4096 total
    ((uint4*)carry)[i] = ((const uint4*)(ocs + (size_t)(SC - 1) * 64 * TH))[i];
}

extern "C" void kernel_launch(void* const* d_in, const int* in_sizes, int n_in,
                              void* d_out, int out_size, void* d_ws, size_t ws_size,
                              hipStream_t stream) {
    const float* x   = (const float*)d_in[0];
    const float* g1  = (const float*)d_in[1];
    const float* b1  = (const float*)d_in[2];
    const float* W1  = (const float*)d_in[3];
    const float* W2  = (const float*)d_in[4];
    const float* g2  = (const float*)d_in[5];
    const float* b2  = (const float*)d_in[6];
    const float* fw1 = (const float*)d_in[7];
    const float* fb1 = (const float*)d_in[8];
    const float* fw2 = (const float*)d_in[9];
    const float* fb2 = (const float*)d_in[10];
    float* out = (float*)d_out;    // output FLOAT32 (reference output dtype)
    char* ws = (char*)d_ws;

    size_t o = 0;
    auto take = [&](size_t n) { size_t r = o; o = (o + n + 255) & ~(size_t)255; return r; };
    float*  Mt    = (float*) (ws + take(64 * 64 * 4));
    u16*    f1t   = (u16*)   (ws + take((size_t)TE * TH * 2));   // fw1^T bf16
    u16*    f2t   = (u16*)   (ws + take((size_t)TH * TE * 2));   // fw2^T bf16
    float2* st1   = (float2*)(ws + take((size_t)TB * TT * 8));
    u16*    carry = (u16*)   (ws + take((size_t)64 * TH * 2));
    const size_t fixed = o;

    // Adaptive slice size: largest SC whose slice buffers fit ws_size
    int SC = 2;
    for (int cand = 128; cand >= 2; cand >>= 1) {
        size_t per = (size_t)cand * 64 * TH * 2 * 3      // c2s + h2s + ocs
                   + (size_t)cand * 64 * TE * 2          // us
                   + 4 * 256;
        if (fixed + per <= ws_size) { SC = cand; break; }
    }
    u16* c2s = (u16*)(ws + take((size_t)SC * 64 * TH * 2));
    u16* h2s = (u16*)(ws + take((size_t)SC * 64 * TH * 2));
    u16* ocs = (u16*)(ws + take((size_t)SC * 64 * TH * 2));
    u16* us  = (u16*)(ws + take((size_t)SC * 64 * TE * 2));
    const int SR = SC * 64;

    make_Mt<<<1, 256, 0, stream>>>(W1, W2, Mt);
    transpose_b<<<dim3(TE / 64, TH / 64), 256, 0, stream>>>(fw1, f1t, TH, TE);
    transpose_b<<<dim3(TH / 64, TE / 64), 256, 0, stream>>>(fw2, f2t, TE, TH);
    ln_stats<<<(TB * TT) / 4, 256, 0, stream>>>(x, st1);

    for (int b = 0; b < TB; ++b) {
        for (int n0 = 0; n0 < NCHUNK; n0 += SC) {
            trilinear_f<<<dim3(SC, TH / 256), 256, 0, stream>>>(x, st1, g1, b1, Mt, c2s, b, n0);
            ln_rows<<<SR / 4, 256, 0, stream>>>(c2s, h2s, g2, b2);
            gemm_bt<1><<<dim3(TE / 128, SR / 128), 256, 0, stream>>>(
                h2s, f1t, us, fb1, (const u16*)nullptr, TE, TH);
            gemm_bt<2><<<dim3(TH / 128, SR / 128), 256, 0, stream>>>(
                us, f2t, ocs, fb2, c2s, TH, TE);
            gather_slice<<<SC * 8, 256, 0, stream>>>(
                ocs, carry, out + ((size_t)b * TT + (size_t)n0 * 32) * TH, n0);
            save_carry<<<16, 256, 0, stream>>>(ocs, carry, SC);
        }
    }
}

// Round 7
// 806.903 us; speedup vs baseline: 4.9088x; 4.9088x over previous
//
#include <hip/hip_runtime.h>
#include <math.h>

// PraxisNano: B=4, T=8192, H=512, E=2048, C=64, stride=32
// Inputs: float32. Output: float32. Internal: bf16 MFMA (m97 staging), __sinf.
// Slices over GLOBAL chunk index gc in [0,1024): b = gc>>8, n = gc&255.
#define TB 4
#define TT 8192
#define TH 512
#define TE 2048
#define NCHUNK 256
#define GCTOT 1024          // TB*NCHUNK

typedef unsigned short u16;
typedef short bf8v __attribute__((ext_vector_type(8)));   // 8 bf16 MFMA frag
typedef float f4v __attribute__((ext_vector_type(4)));    // MFMA accumulator

__device__ __forceinline__ float bu2f(u16 u) {
    unsigned int x = ((unsigned int)u) << 16; float f; __builtin_memcpy(&f, &x, 4); return f;
}
__device__ __forceinline__ u16 f2bu(float f) {
    unsigned int x; __builtin_memcpy(&x, &f, 4);
    x = x + 0x7fffu + ((x >> 16) & 1u);   // RNE
    return (u16)(x >> 16);
}

// ---------------- composite TriLinear matrix, transposed: Mt[s][t] = ((W2.tri)(W1.tri))[t][s]
__global__ __launch_bounds__(256) void make_Mt(const float* __restrict__ W1,
                                               const float* __restrict__ W2,
                                               float* __restrict__ Mt) {
    __shared__ float w1[64 * 64];
    __shared__ float w2[64 * 64];
    for (int i = threadIdx.x; i < 4096; i += 256) { w1[i] = W1[i]; w2[i] = W2[i]; }
    __syncthreads();
    for (int i = threadIdx.x; i < 4096; i += 256) {
        int t = i >> 6, s = i & 63;
        float a = 0.f;
        if (t >= s) for (int k = s; k <= t; ++k) a += w2[t * 64 + k] * w1[k * 64 + s];
        Mt[s * 64 + t] = a;
    }
}

// ---------------- transpose f32 (R x C) -> bf16 (C x R)
__global__ __launch_bounds__(256) void transpose_b(const float* __restrict__ in,
                                                   u16* __restrict__ out, int R, int C) {
    __shared__ u16 tile[64][65];
    const int bx = blockIdx.x, by = blockIdx.y;
    const int tx = threadIdx.x & 63, ty = threadIdx.x >> 6;
#pragma unroll
    for (int i = 0; i < 16; ++i) {
        int r = ty + i * 4;
        tile[r][tx] = f2bu(in[(size_t)(by * 64 + r) * C + bx * 64 + tx]);
    }
    __syncthreads();
#pragma unroll
    for (int i = 0; i < 16; ++i) {
        int r = ty + i * 4;
        out[(size_t)(bx * 64 + r) * R + by * 64 + tx] = tile[tx][r];
    }
}

// ---------------- LN1 stats per x-row (mean, rstd)
__global__ __launch_bounds__(256) void ln_stats(const float* __restrict__ x,
                                                float2* __restrict__ st) {
    const int wave = threadIdx.x >> 6, lane = threadIdx.x & 63;
    const size_t row = (size_t)blockIdx.x * 4 + wave;
    const float4* p = (const float4*)(x + row * TH);
    float4 a = p[lane * 2], b = p[lane * 2 + 1];
    float s = 0.f, q = 0.f;
    float v[8] = {a.x, a.y, a.z, a.w, b.x, b.y, b.z, b.w};
#pragma unroll
    for (int i = 0; i < 8; ++i) { s += v[i]; q += v[i] * v[i]; }
#pragma unroll
    for (int o = 32; o; o >>= 1) { s += __shfl_xor(s, o); q += __shfl_xor(q, o); }
    const float mean = s * (1.f / TH);
    float var = q * (1.f / TH) - mean * mean;
    if (var < 0.f) var = 0.f;
    if (lane == 0) st[row] = make_float2(mean, rsqrtf(var + 1e-5f));
}

// ---------------- LN2: bf16 rows in -> bf16 rows out, f32 gamma/beta
__global__ __launch_bounds__(256) void ln_rows(const u16* __restrict__ in,
                                               u16* __restrict__ out,
                                               const float* __restrict__ g,
                                               const float* __restrict__ b) {
    const int wave = threadIdx.x >> 6, lane = threadIdx.x & 63;
    const size_t row = (size_t)blockIdx.x * 4 + wave;
    uint4 raw = *((const uint4*)(in + row * TH) + lane);
    const u16* e = (const u16*)&raw;
    float v[8]; float s = 0.f, q = 0.f;
#pragma unroll
    for (int i = 0; i < 8; ++i) { v[i] = bu2f(e[i]); s += v[i]; q += v[i] * v[i]; }
#pragma unroll
    for (int o = 32; o; o >>= 1) { s += __shfl_xor(s, o); q += __shfl_xor(q, o); }
    const float mean = s * (1.f / TH);
    float var = q * (1.f / TH) - mean * mean;
    if (var < 0.f) var = 0.f;
    const float rstd = rsqrtf(var + 1e-5f);
    float4 g0 = ((const float4*)g)[lane * 2], g1 = ((const float4*)g)[lane * 2 + 1];
    float4 b0 = ((const float4*)b)[lane * 2], b1 = ((const float4*)b)[lane * 2 + 1];
    float ge[8] = {g0.x, g0.y, g0.z, g0.w, g1.x, g1.y, g1.z, g1.w};
    float be[8] = {b0.x, b0.y, b0.z, b0.w, b1.x, b1.y, b1.z, b1.w};
    u16 ov[8];
#pragma unroll
    for (int i = 0; i < 8; ++i) ov[i] = f2bu((v[i] - mean) * rstd * ge[i] + be[i]);
    *((uint4*)(out + row * TH) + lane) = *(uint4*)ov;
}

// ---------------- TriLinear for one slice (global-chunk indexed), LN1 fused via stats
__global__ __launch_bounds__(256) void trilinear_f(const float* __restrict__ x,
                                                   const float2* __restrict__ st,
                                                   const float* __restrict__ g,
                                                   const float* __restrict__ bb,
                                                   const float* __restrict__ Mt,
                                                   u16* __restrict__ c2s,
                                                   int gc0) {
    const int ln = blockIdx.x;
    const int gc = gc0 + ln;
    const int b = gc >> 8, n = gc & 255;
    const int h = (blockIdx.y << 8) + threadIdx.x;
    const int base = n * 32;
    const float gh = g[h], bh = bb[h];
    float acc[64];
#pragma unroll
    for (int t = 0; t < 64; ++t) acc[t] = 0.f;
    for (int s = 0; s < 64; ++s) {
        int pos = base + s; if (pos > TT - 1) pos = TT - 1;   // clamped rows hit only M==0 weights for read outputs
        const size_t ro = (size_t)b * TT + pos;
        const float2 mr = st[ro];
        const float cn = (x[ro * TH + h] - mr.x) * mr.y * gh + bh;
        const float* m = Mt + s * 64;
#pragma unroll
        for (int t = 0; t < 64; ++t) acc[t] += m[t] * cn;
    }
#pragma unroll
    for (int t = 0; t < 64; ++t) {
        int pos = base + t; if (pos > TT - 1) pos = TT - 1;
        const float resid = x[((size_t)b * TT + pos) * TH + h];
        c2s[(size_t)(ln * 64 + t) * TH + h] = f2bu(acc[t] + resid);
    }
}

// ---------------- MFMA GEMM, B^T input, m97 global_load_lds width-16 staging
// MODE 1: C = __sinf(acc + bias);  MODE 2: C = acc + bias + addp
template <int MODE>
__global__ __launch_bounds__(256) void gemm_bt(const u16* __restrict__ A,    // M x K bf16
                                               const u16* __restrict__ Bt,   // N x K bf16
                                               u16* __restrict__ C,          // M x N bf16
                                               const float* __restrict__ bias,
                                               const u16* __restrict__ addp,
                                               int N, int K) {
    __shared__ u16 lA[128 * 64];
    __shared__ u16 lB[128 * 64];
    const int tid = threadIdx.x;
    const int wave = tid >> 6;
    const int lane = tid & 63;
    const int wr = wave >> 1;
    const int wc = wave & 1;
    const int bm = blockIdx.y << 7;
    const int bn = blockIdx.x << 7;
    const int lrow = lane >> 3;            // 0..7
    const int lcol = (lane & 7) << 3;      // 0..56 (x8 bf16 = 16B)
    const int fr = lane & 15;
    const int fq = (lane >> 4) << 3;
    f4v acc[4][4] = {};

    for (int kb = 0; kb < K; kb += 64) {
#pragma unroll
        for (int i = 0; i < 4; ++i) {
            const int r = (wave << 5) + (i << 3);      // wave-uniform LDS base row
            const u16* ga = A + (size_t)(bm + r + lrow) * K + kb + lcol;
            __builtin_amdgcn_global_load_lds((const __attribute__((address_space(1))) void*)ga,
                                             (__attribute__((address_space(3))) void*)(lA + r * 64),
                                             16, 0, 0);
            const u16* gb = Bt + (size_t)(bn + r + lrow) * K + kb + lcol;
            __builtin_amdgcn_global_load_lds((const __attribute__((address_space(1))) void*)gb,
                                             (__attribute__((address_space(3))) void*)(lB + r * 64),
                                             16, 0, 0);
        }
        __syncthreads();
#pragma unroll
        for (int ks = 0; ks < 64; ks += 32) {
            bf8v af[4], bf[4];
#pragma unroll
            for (int mi = 0; mi < 4; ++mi)
                af[mi] = *(const bf8v*)(lA + ((wr << 6) + (mi << 4) + fr) * 64 + ks + fq);
#pragma unroll
            for (int ni = 0; ni < 4; ++ni)
                bf[ni] = *(const bf8v*)(lB + ((wc << 6) + (ni << 4) + fr) * 64 + ks + fq);
#pragma unroll
            for (int mi = 0; mi < 4; ++mi)
#pragma unroll
                for (int ni = 0; ni < 4; ++ni)
                    acc[mi][ni] = __builtin_amdgcn_mfma_f32_16x16x32_bf16(af[mi], bf[ni], acc[mi][ni], 0, 0, 0);
        }
        __syncthreads();
    }

    const int rq = (lane >> 4) << 2;   // C/D: col=lane&15, row=(lane>>4)*4+reg (m89/m91)
#pragma unroll
    for (int mi = 0; mi < 4; ++mi) {
#pragma unroll
        for (int ni = 0; ni < 4; ++ni) {
            const int col = bn + (wc << 6) + (ni << 4) + fr;
            const float bv = bias[col];
#pragma unroll
            for (int r = 0; r < 4; ++r) {
                const int row = bm + (wr << 6) + (mi << 4) + rq + r;
                float v = acc[mi][ni][r] + bv;
                if (MODE == 1) v = __sinf(v);
                else v += bu2f(addp[(size_t)row * N + col]);
                C[(size_t)row * N + col] = f2bu(v);
            }
        }
    }
}

// ---------------- per-slice gather -> FLOAT32 output (linear position mapping)
__global__ __launch_bounds__(256) void gather_slice(const u16* __restrict__ ocs,
                                                    const u16* __restrict__ carry,
                                                    float* __restrict__ out,
                                                    int gc0) {
    const int idx = blockIdx.x * 256 + threadIdx.x;   // vec8 id within slice
    const int h8 = idx & 63;                          // TH/8
    const int prow = idx >> 6;                        // 0 .. SC*32-1
    const int ap = gc0 * 32 + prow;                   // linear (b,t) position index
    const int b = ap >> 13, t = ap & 8191;
    const int n = t >> 5, c = t & 31;
    const int ln = (b << 8) + n - gc0;                // covering chunk, slice-local
    uint4 r1 = *((const uint4*)ocs + (size_t)(ln * 64 + c) * 64 + h8);
    const u16* e1 = (const u16*)&r1;
    float ov[8];
    if (t < 32) {
#pragma unroll
        for (int i = 0; i < 8; ++i) ov[i] = bu2f(e1[i]);
    } else {
        uint4 r0;
        if (ln == 0) r0 = *((const uint4*)carry + (size_t)(c + 32) * 64 + h8);
        else         r0 = *((const uint4*)ocs + (size_t)((ln - 1) * 64 + c + 32) * 64 + h8);
        const u16* e0 = (const u16*)&r0;
#pragma unroll
        for (int i = 0; i < 8; ++i) ov[i] = 0.5f * (bu2f(e1[i]) + bu2f(e0[i]));
    }
    float4* dst = (float4*)(out + (size_t)ap * TH + h8 * 8);
    dst[0] = make_float4(ov[0], ov[1], ov[2], ov[3]);
    dst[1] = make_float4(ov[4], ov[5], ov[6], ov[7]);
}

// ---------------- save last chunk of slice for next slice's boundary
__global__ __launch_bounds__(256) void save_carry(const u16* __restrict__ ocs,
                                                  u16* __restrict__ carry, int SC) {
    const int i = blockIdx.x * 256 + threadIdx.x;     // uint4 id, 4096 total
    ((uint4*)carry)[i] = ((const uint4*)(ocs + (size_t)(SC - 1) * 64 * TH))[i];
}

extern "C" void kernel_launch(void* const* d_in, const int* in_sizes, int n_in,
                              void* d_out, int out_size, void* d_ws, size_t ws_size,
                              hipStream_t stream) {
    const float* x   = (const float*)d_in[0];
    const float* g1  = (const float*)d_in[1];
    const float* b1  = (const float*)d_in[2];
    const float* W1  = (const float*)d_in[3];
    const float* W2  = (const float*)d_in[4];
    const float* g2  = (const float*)d_in[5];
    const float* b2  = (const float*)d_in[6];
    const float* fw1 = (const float*)d_in[7];
    const float* fb1 = (const float*)d_in[8];
    const float* fw2 = (const float*)d_in[9];
    const float* fb2 = (const float*)d_in[10];
    float* out = (float*)d_out;
    char* ws = (char*)d_ws;

    size_t o = 0;
    auto take = [&](size_t n) { size_t r = o; o = (o + n + 255) & ~(size_t)255; return r; };
    float*  Mt    = (float*) (ws + take(64 * 64 * 4));
    u16*    f1t   = (u16*)   (ws + take((size_t)TE * TH * 2));
    u16*    f2t   = (u16*)   (ws + take((size_t)TH * TE * 2));
    float2* st1   = (float2*)(ws + take((size_t)TB * TT * 8));
    u16*    carry = (u16*)   (ws + take((size_t)64 * TH * 2));
    const size_t fixed = o;

    // Adaptive slice size (global chunks per slice), capped at 256 so us stays L3-resident.
    int SC = 2;
    for (int cand = 256; cand >= 2; cand >>= 1) {
        size_t per = (size_t)cand * 64 * (TH * 2 * 3 + TE * 2) + 4 * 256;
        if (fixed + per <= ws_size) { SC = cand; break; }
    }
    u16* c2s = (u16*)(ws + take((size_t)SC * 64 * TH * 2));
    u16* h2s = (u16*)(ws + take((size_t)SC * 64 * TH * 2));
    u16* ocs = (u16*)(ws + take((size_t)SC * 64 * TH * 2));
    u16* us  = (u16*)(ws + take((size_t)SC * 64 * TE * 2));
    const int SR = SC * 64;

    make_Mt<<<1, 256, 0, stream>>>(W1, W2, Mt);
    transpose_b<<<dim3(TE / 64, TH / 64), 256, 0, stream>>>(fw1, f1t, TH, TE);
    transpose_b<<<dim3(TH / 64, TE / 64), 256, 0, stream>>>(fw2, f2t, TE, TH);
    ln_stats<<<(TB * TT) / 4, 256, 0, stream>>>(x, st1);

    for (int gc0 = 0; gc0 < GCTOT; gc0 += SC) {
        trilinear_f<<<dim3(SC, TH / 256), 256, 0, stream>>>(x, st1, g1, b1, Mt, c2s, gc0);
        ln_rows<<<SR / 4, 256, 0, stream>>>(c2s, h2s, g2, b2);
        gemm_bt<1><<<dim3(TE / 128, SR / 128), 256, 0, stream>>>(
            h2s, f1t, us, fb1, (const u16*)nullptr, TE, TH);
        gemm_bt<2><<<dim3(TH / 128, SR / 128), 256, 0, stream>>>(
            us, f2t, ocs, fb2, c2s, TH, TE);
        gather_slice<<<SC * 8, 256, 0, stream>>>(ocs, carry, out, gc0);
        save_carry<<<16, 256, 0, stream>>>(ocs, carry, SC);
    }
}